// Round 18
// baseline (198.510 us; speedup 1.0000x reference)
//
#include <hip/hip_runtime.h>
#include <math.h>

#define BATCH 524288
#define VEC 512
#define RPB 128   // contiguous rows per block; 4096 blocks x 128 rows = 524288

typedef float f32x4 __attribute__((ext_vector_type(4)));

// Accurate sincos of an f32 phase value: f64 reduction by pi/2 of the exact
// f32 input, then f32 minimax kernels on [-pi/4, pi/4] (~1e-7 abs error).
// Correctness-proven in round 10 (absmax 3.9e-3). DO NOT change.
__device__ __forceinline__ void sincos_acc(float phf, float& s, float& c) {
    const double two_over_pi = 0.6366197723675814;
    const double pio2        = 1.5707963267948966;
    const double ph  = (double)phf;                 // exact
    const double nd  = rint(ph * two_over_pi);      // |nd| <= ~3.4e4, exact int
    const double red = fma(-nd, pio2, ph);          // |red| <= pi/4, err ~1e-12
    const int    q   = ((int)nd) & 3;               // correct for negative nd
    const float  r   = (float)red;
    const float  r2  = r * r;
    float sp = fmaf(r2, 2.7183114939898219e-6f, -1.9839334836096632e-4f);
    sp = fmaf(r2, sp, 8.3333293858894632e-3f);
    sp = fmaf(r2, sp, -1.6666666641626524e-1f);
    sp = r * fmaf(r2, sp, 1.0f);
    float cp = fmaf(r2, 2.4390448796277409e-5f, -1.3886763774609929e-3f);
    cp = fmaf(r2, cp, 4.1666623323739063e-2f);
    cp = fmaf(r2, cp, -4.9999999725103100e-1f);
    cp = fmaf(r2, cp, 1.0f);
    const bool swp = (q & 1);
    float ss = swp ? cp : sp;
    float cc = swp ? sp : cp;
    s = (q & 2)       ? -ss : ss;
    c = ((q + 1) & 2) ? -cc : cc;
}

// Tiny prologue: build the 256-entry frequency table in d_ws.
// FREQUENCY CHAIN -- correctness-critical, verified round 10 (absmax 3.9e-3):
// ref e-chain = fast-math reciprocal division (XLA:CPU arcp):
//   e = (i * fl32(1/255)) * 4, NOT true f32 division.
// pow = accurate exp10 -> matched by CR f64 pow. Bit-identical to R13/R17.
__global__ void freq_table_kernel(float* __restrict__ fw) {
    const int i = threadIdx.x;                  // 0..255
    const float RCP255 = 1.0f / 255.0f;         // compile-time fl32(1/255)
    const float e = ((float)i * RCP255) * 4.0f;
    fw[i] = (float)pow(10.0, (double)e);
}

// Main kernel: no pow call -> lean VGPR -> high occupancy (A/B vs R13:
// occupancy/store-depth theory; loop numerics bit-identical).
__global__ __launch_bounds__(256, 6) void input_layer_kernel(
        const float* __restrict__ x, const float* __restrict__ fw,
        float* __restrict__ out) {
    __shared__ float xs[RPB];
    const int tid  = threadIdx.x;
    const int base = blockIdx.x * RPB;          // this block's contiguous row range

    // One-time x stage: 128 floats = 512 B coalesced. Hot loop does ZERO
    // global reads -- pure write stream like fillBuffer.
    if (tid < RPB) xs[tid] = x[base + tid];

    const int   q  = tid & 127;                 // float4 index within row
    const float f0 = fw[2 * q];                 // table freqs (L2-resident)
    const float f1 = fw[2 * q + 1];

    __syncthreads();

    const int half = tid >> 7;                  // 0 or 1: which of the 2 rows/iter
    for (int k = 0; k < RPB; k += 2) {
        const int   r  = k + half;              // wave-uniform -> LDS broadcast read
        const float xv = xs[r];
        float s0, c0, s1, c1;
        sincos_acc(xv * f0, s0, c0);            // phase rounded to f32, like the ref
        sincos_acc(xv * f1, s1, c1);
        f32x4 o = {s0, c0, s1, c1};
        f32x4* dst = reinterpret_cast<f32x4*>(out + (size_t)(base + r) * VEC) + q;
        *dst = o;                               // cached store (R13 A/B winner)
    }
}

extern "C" void kernel_launch(void* const* d_in, const int* in_sizes, int n_in,
                              void* d_out, int out_size, void* d_ws, size_t ws_size,
                              hipStream_t stream) {
    const float* x = (const float*)d_in[0];
    float* out = (float*)d_out;
    float* fw  = (float*)d_ws;                  // 1 KB frequency table
    freq_table_kernel<<<1, 256, 0, stream>>>(fw);
    input_layer_kernel<<<BATCH / RPB, 256, 0, stream>>>(x, fw, out);
}